// Round 5
// baseline (170.190 us; speedup 1.0000x reference)
//
#include <hip/hip_runtime.h>
#include <math.h>

// SSIM loss, fp32, N=16 C=3 H=W=512, 11x11 Gaussian sigma=1.5, zero-padded,
// separable — both blur passes on the MFMA pipe (16x16x32 bf16).
// R13 = barrier-free 1-wave blocks to break phase-locking:
//   R12 diagnosis: slot time (2285 cyc) == one block's serial chain; with 30
//   resident waves VALUBusy should be ~75% but measured 34% -> waves are
//   phase-locked by intra-block barriers + lockstep neighbor dispatch.
//   Fix: each 64-lane wave computes one 16x16 output tile END-TO-END:
//     - V pass on 2 x-chunks (32-col window = 16 own + 10 halo + 6 pad),
//       10 MFMA; private vb[5][16][40] (6.4 KB, stride 40 -> <=2-way banks,
//       16B-aligned b128 reads); H pass 5 MFMA; epilogue; 6-shfl reduce;
//       ONE global store. Zero __syncthreads coupling across waves.
//   24 LDS-limited independent waves/CU at self-staggered phases.
//   x-halo re-reads (adjacent blocks, different XCDs) hit die-level L3
//   (input 100 MB << 256 MB) -> HBM FETCH stays ~compulsory.
//   GXD=32 (y-neighbors differ by 32 ≡ 0 mod 8 XCDs -> y-halo stays L2-hot,
//   the R11 lesson). Host-side memcpy replaced by tiny winit kernel
//   (pageable hipMemcpyAsync cost ~5-10 us of stream time).
// Math/fragments bit-identical to R12 per output pixel.

#define IMG 512
#define GXD 32
#define GYD 32
#define GZD 48
#define NB (GXD * GYD * GZD)    // 49152 blocks (1 wave each)
#define VBS 40                  // vb row stride in bf16 (80 B)
#define C1c 0.0001f
#define C2c 0.0009f
#define NTOTAL 12582912.0f
#define WS_NEED (1024 + (size_t)NB * 4)

typedef short bf16x8 __attribute__((ext_vector_type(8)));
typedef float f32x4 __attribute__((ext_vector_type(4)));
typedef float f32x2 __attribute__((ext_vector_type(2)));

struct GaussB { unsigned short gb[11]; };   // bf16 weights (host-RNE)

// pack bf16(a) low 16, bf16(b) high 16 — one v_perm_b32 (truncation)
__device__ __forceinline__ unsigned int pkbf(float a, float b) {
    return __builtin_amdgcn_perm(__float_as_uint(b), __float_as_uint(a),
                                 0x07060302u);
}

// ---------------- shared device pieces (identical math to R12) -------------

__device__ __forceinline__ void load_px(const float* __restrict__ pbase,
                                        const float* __restrict__ tbase,
                                        int gx, bool xin, int gy0,
                                        float (&pv)[8], float (&tv)[8]) {
    const bool ok = xin & (gy0 >= 0) & (gy0 <= IMG - 8);
    if (ok) {
        const float* pp = pbase + gy0 * IMG + gx;
        const float* tp = tbase + gy0 * IMG + gx;
        #pragma unroll
        for (int j = 0; j < 8; ++j) {
            pv[j] = pp[j * IMG];
            tv[j] = tp[j * IMG];
        }
    } else {
        #pragma unroll
        for (int j = 0; j < 8; ++j) {
            int gy = gy0 + j;
            bool in = xin && ((unsigned)gy < (unsigned)IMG);
            int idx = in ? (gy * IMG + gx) : 0;
            float a = pbase[idx];
            float b = tbase[idx];
            pv[j] = in ? a : 0.0f;
            tv[j] = in ? b : 0.0f;
        }
    }
}

__device__ __forceinline__ void pass_v_body(
    const float (&pv)[8], const float (&tv)[8], bf16x8 wfrag,
    unsigned short (*vb)[16][VBS], int n16, int vcol) {
    const f32x4 z = {0.0f, 0.0f, 0.0f, 0.0f};
    const f32x2 halfv = {0.5f, 0.5f};
    f32x2 p2[4], t2[4];
    #pragma unroll
    for (int h = 0; h < 4; ++h) {
        f32x2 pr = {pv[2*h], pv[2*h+1]};
        f32x2 tr = {tv[2*h], tv[2*h+1]};
        p2[h] = pr * halfv + halfv;     // v_pk_fma_f32
        t2[h] = tr * halfv + halfv;
    }
    #pragma unroll
    for (int ch = 0; ch < 5; ++ch) {
        union { bf16x8 v; unsigned int u[4]; } f;
        #pragma unroll
        for (int h = 0; h < 4; ++h) {
            f32x2 q;
            if      (ch == 0) q = p2[h];
            else if (ch == 1) q = t2[h];
            else if (ch == 2) q = p2[h] * p2[h];   // v_pk_mul_f32
            else if (ch == 3) q = t2[h] * t2[h];
            else              q = p2[h] * t2[h];
            f.u[h] = pkbf(q.x, q.y);
        }
        f32x4 d = __builtin_amdgcn_mfma_f32_16x16x32_bf16(f.v, wfrag, z, 0, 0, 0);
        union { ushort4 s; unsigned int u[2]; } pk;
        pk.u[0] = pkbf(d[0], d[1]);
        pk.u[1] = pkbf(d[2], d[3]);
        *(ushort4*)&vb[ch][n16][vcol] = pk.s;
    }
}

__device__ __forceinline__ float pass_h_body(
    unsigned short (*vb)[16][VBS], bf16x8 wfrag, int n16, int quad) {
    const f32x4 z = {0.0f, 0.0f, 0.0f, 0.0f};
    float lsum = 0.0f;
    f32x4 r[5];
    #pragma unroll
    for (int ch = 0; ch < 5; ++ch) {
        bf16x8 a = *(const bf16x8*)&vb[ch][n16][8 * quad];
        r[ch] = __builtin_amdgcn_mfma_f32_16x16x32_bf16(a, wfrag, z, 0, 0, 0);
    }
    const f32x2 twov = {2.0f, 2.0f};
    const f32x2 c1v  = {C1c, C1c};
    const f32x2 c2v  = {C2c, C2c};
    #pragma unroll
    for (int jj = 0; jj < 2; ++jj) {
        f32x2 mp  = {r[0][2*jj], r[0][2*jj+1]};
        f32x2 mt  = {r[1][2*jj], r[1][2*jj+1]};
        f32x2 epp = {r[2][2*jj], r[2][2*jj+1]};
        f32x2 ett = {r[3][2*jj], r[3][2*jj+1]};
        f32x2 ept = {r[4][2*jj], r[4][2*jj+1]};
        f32x2 mp2 = mp * mp;
        f32x2 mt2 = mt * mt;
        f32x2 mpt = mp * mt;
        f32x2 sp_ = epp - mp2;
        f32x2 st_ = ett - mt2;
        f32x2 spt = ept - mpt;
        f32x2 num = (mpt * twov + c1v) * (spt * twov + c2v);
        f32x2 den = (mp2 + mt2 + c1v) * (sp_ + st_ + c2v);
        lsum = fmaf(num.x, __builtin_amdgcn_rcpf(den.x), lsum);
        lsum = fmaf(num.y, __builtin_amdgcn_rcpf(den.y), lsum);
    }
    return lsum;
}

// ---------------- main kernel, workspace path (R13) -----------------------

__global__ __launch_bounds__(64, 6) void ssim_main_ws(
    const float* __restrict__ pred,
    const float* __restrict__ target,
    const unsigned short* __restrict__ wtab,   // 16x32 bf16 W matrix in ws
    float* __restrict__ partials)              // NB per-block partials
{
    __shared__ unsigned short vb[5][16][VBS];     // 6400 B, private to wave

    const int lane = threadIdx.x;
    const int quad = lane >> 4;
    const int n16  = lane & 15;
    const int c0   = blockIdx.x * 16;          // own output cols c0..c0+15
    const int ty0  = blockIdx.y * 16;
    const float* __restrict__ pbase = pred   + (size_t)blockIdx.z * (IMG * IMG);
    const float* __restrict__ tbase = target + (size_t)blockIdx.z * (IMG * IMG);

    const int gy0 = ty0 - 5 + quad * 8;        // first of 8 input rows
    const int gxA = c0 - 5 + n16;              // chunk A: x-window 0..15
    const int gxB = c0 + 11 + n16;             // chunk B: x-window 16..31

    // wfrag: one L2-hot 16B load, overlaps the pixel loads
    const bf16x8 wfrag = *(const bf16x8*)(wtab + n16 * 32 + quad * 8);

    float pvA[8], tvA[8], pvB[8], tvB[8];
    load_px(pbase, tbase, gxA, (unsigned)gxA < (unsigned)IMG, gy0, pvA, tvA);
    load_px(pbase, tbase, gxB, (unsigned)gxB < (unsigned)IMG, gy0, pvB, tvB);

    pass_v_body(pvA, tvA, wfrag, vb, n16, 4 * quad);
    pass_v_body(pvB, tvB, wfrag, vb, n16, 16 + 4 * quad);
    __syncthreads();   // 1-wave block: compiles to lgkm drain + trivial barrier

    float lsum = pass_h_body(vb, wfrag, n16, quad);

    #pragma unroll
    for (int off = 32; off > 0; off >>= 1)
        lsum += __shfl_down(lsum, off, 64);
    if (lane == 0) {
        int bid = blockIdx.x + GXD * (blockIdx.y + GYD * blockIdx.z);
        partials[bid] = lsum;
    }
}

// W-table init on device (replaces pageable hipMemcpyAsync)
__global__ void ssim_winit(unsigned short* __restrict__ wtab, GaussB gwb) {
    int idx = threadIdx.x;            // 512 threads
    int i = idx >> 5, k = idx & 31, d = k - i;
    wtab[idx] = (d >= 0 && d <= 10) ? gwb.gb[d] : 0;
}

// ---------------- atomic fallback (ws too small): same structure ----------

__global__ __launch_bounds__(64, 6) void ssim_main_atomic(
    const float* __restrict__ pred,
    const float* __restrict__ target,
    float* __restrict__ sink,
    GaussB gwb)
{
    __shared__ unsigned short Wmat[16][32];
    __shared__ unsigned short vb[5][16][VBS];

    const int lane = threadIdx.x;
    const int quad = lane >> 4;
    const int n16  = lane & 15;
    const int c0   = blockIdx.x * 16;
    const int ty0  = blockIdx.y * 16;
    const float* __restrict__ pbase = pred   + (size_t)blockIdx.z * (IMG * IMG);
    const float* __restrict__ tbase = target + (size_t)blockIdx.z * (IMG * IMG);

    const int gy0 = ty0 - 5 + quad * 8;
    const int gxA = c0 - 5 + n16;
    const int gxB = c0 + 11 + n16;

    float pvA[8], tvA[8], pvB[8], tvB[8];
    load_px(pbase, tbase, gxA, (unsigned)gxA < (unsigned)IMG, gy0, pvA, tvA);
    load_px(pbase, tbase, gxB, (unsigned)gxB < (unsigned)IMG, gy0, pvB, tvB);

    #pragma unroll
    for (int r = 0; r < 8; ++r) {
        int idx = lane + 64 * r;
        int i = idx >> 5, k = idx & 31, d = k - i;
        Wmat[i][k] = (d >= 0 && d <= 10) ? gwb.gb[d] : 0;
    }
    __syncthreads();
    const bf16x8 wfrag = *(const bf16x8*)&Wmat[n16][quad * 8];

    pass_v_body(pvA, tvA, wfrag, vb, n16, 4 * quad);
    pass_v_body(pvB, tvB, wfrag, vb, n16, 16 + 4 * quad);
    __syncthreads();

    float lsum = pass_h_body(vb, wfrag, n16, quad);

    #pragma unroll
    for (int off = 32; off > 0; off >>= 1)
        lsum += __shfl_down(lsum, off, 64);
    if (lane == 0)
        atomicAdd(sink, lsum);
}

// ---------------- reductions ----------------------------------------------

__global__ __launch_bounds__(1024) void ssim_reduce(const float* __restrict__ partials,
                                                    float* __restrict__ out)
{
    __shared__ float red[16];
    const int tid = threadIdx.x;
    float s = 0.0f;
    const float4* p4 = (const float4*)partials;
    #pragma unroll
    for (int j = 0; j < NB / 4096; ++j) {   // 49152/4 = 12288 f4 / 1024
        float4 v = p4[tid + 1024 * j];
        s += v.x + v.y + v.z + v.w;
    }
    #pragma unroll
    for (int off = 32; off > 0; off >>= 1)
        s += __shfl_down(s, off, 64);
    if ((tid & 63) == 0) red[tid >> 6] = s;
    __syncthreads();
    if (tid == 0) {
        float t = 0.0f;
        #pragma unroll
        for (int k = 0; k < 16; ++k) t += red[k];
        out[0] = 1.0f - t / NTOTAL;
    }
}

__global__ void ssim_zero(float* accum) { accum[0] = 0.0f; }
__global__ void ssim_final(const float* accum, float* out) {
    out[0] = 1.0f - accum[0] / NTOTAL;
}

// ---------------- host ----------------------------------------------------

extern "C" void kernel_launch(void* const* d_in, const int* in_sizes, int n_in,
                              void* d_out, int out_size, void* d_ws, size_t ws_size,
                              hipStream_t stream) {
    const float* pred   = (const float*)d_in[0];
    const float* target = (const float*)d_in[1];
    float* out = (float*)d_out;

    // Gaussian weights in double, RNE-rounded to bf16 on host
    GaussB gwb;
    double vals[11], s = 0.0;
    for (int i = 0; i < 11; ++i) {
        double d = (double)i - 5.0;
        vals[i] = exp(-(d * d) / (2.0 * 1.5 * 1.5));
        s += vals[i];
    }
    for (int i = 0; i < 11; ++i) {
        float f = (float)(vals[i] / s);
        unsigned int u;
        __builtin_memcpy(&u, &f, 4);
        unsigned int rounded = (u + 0x7FFFu + ((u >> 16) & 1u)) >> 16;  // RNE
        gwb.gb[i] = (unsigned short)rounded;
    }

    dim3 grid(GXD, GYD, GZD);   // 32 x 32 x 48 = 49152 one-wave blocks
    if (ws_size >= WS_NEED) {
        unsigned short* wtab = (unsigned short*)d_ws;            // 1 KB
        float* partials = (float*)((char*)d_ws + 1024);          // NB floats
        ssim_winit<<<1, 512, 0, stream>>>(wtab, gwb);
        ssim_main_ws<<<grid, 64, 0, stream>>>(pred, target, wtab, partials);
        ssim_reduce<<<1, 1024, 0, stream>>>(partials, out);
    } else {
        float* accum = (float*)d_ws;
        ssim_zero<<<1, 1, 0, stream>>>(accum);
        ssim_main_atomic<<<grid, 64, 0, stream>>>(pred, target, accum, gwb);
        ssim_final<<<1, 1, 0, stream>>>(accum, out);
    }
}

// Round 6
// 145.784 us; speedup vs baseline: 1.1674x; 1.1674x over previous
//
#include <hip/hip_runtime.h>
#include <math.h>

// SSIM loss, fp32, N=16 C=3 H=W=512, 11x11 Gaussian sigma=1.5, zero-padded,
// separable — both blur passes on the MFMA pipe (16x16x32 bf16).
// R14 = R12's exact tile (16x64, the only footprint that achieves
// compulsory FETCH=92MB; R11/R13 tile changes doubled it) with the
// wave-correlation broken:
//   - each 64-lane wave owns one FULL 16x64 tile: 5 V-chunks + 4 H-chunks,
//     software-pipelined in-wave (load c+1 issued before pass_V(c), depth-2
//     register dbuf). Straight-line, ZERO barriers -> nothing drains vmcnt;
//     compiler emits counted waits. 80 loads spread across the wave's life
//     instead of R12's single 16-load burst (load-issue density 5x).
//   - blocks = 2 independent waves (y-adjacent tiles, same-CU L1 halo
//     reuse), disjoint LDS halves, no __syncthreads in the main kernel.
//   - vb stride 88->72 (23KB/block) -> 7 blocks x 2 = 14 decorrelated
//     self-pipelined waves/CU. Occupancy % will DROP (~42%) by design.
//   - per-output math/fragments bit-identical to R12 (same chunks, same
//     vb contents, same epilogue) -> absmax unchanged.
// grid 8x16x48 = 6144 blocks; GXD=8 == XCD count (y-neighbor blocks differ
// by 8 ≡ 0 mod 8 -> same XCD, vertical halo L2-hot — the R11 lesson).

#define IMG 512
#define GXD 8
#define GYD 16
#define GZD 48
#define NB (GXD * GYD * GZD)    // 6144 blocks
#define NPART (NB * 2)          // per-wave partials
#define VBS 72                  // vb row stride in bf16 (144 B, 16B-aligned)
#define C1c 0.0001f
#define C2c 0.0009f
#define NTOTAL 12582912.0f
#define WS_NEED (1024 + (size_t)NPART * 4)

typedef short bf16x8 __attribute__((ext_vector_type(8)));
typedef float f32x4 __attribute__((ext_vector_type(4)));
typedef float f32x2 __attribute__((ext_vector_type(2)));

struct GaussB { unsigned short gb[11]; };   // bf16 weights (host-RNE)

// pack bf16(a) low 16, bf16(b) high 16 — one v_perm_b32 (truncation)
__device__ __forceinline__ unsigned int pkbf(float a, float b) {
    return __builtin_amdgcn_perm(__float_as_uint(b), __float_as_uint(a),
                                 0x07060302u);
}

// ---------------- shared device pieces (identical math to R12) -------------

__device__ __forceinline__ void load_px(const float* __restrict__ pbase,
                                        const float* __restrict__ tbase,
                                        int gx, int gy0,
                                        float (&pv)[8], float (&tv)[8]) {
    const bool xin = (unsigned)gx < (unsigned)IMG;
    const bool ok = xin & (gy0 >= 0) & (gy0 <= IMG - 8);
    if (ok) {
        const float* pp = pbase + gy0 * IMG + gx;
        const float* tp = tbase + gy0 * IMG + gx;
        #pragma unroll
        for (int j = 0; j < 8; ++j) {
            pv[j] = pp[j * IMG];
            tv[j] = tp[j * IMG];
        }
    } else {
        #pragma unroll
        for (int j = 0; j < 8; ++j) {
            int gy = gy0 + j;
            bool in = xin && ((unsigned)gy < (unsigned)IMG);
            int idx = in ? (gy * IMG + gx) : 0;
            float a = pbase[idx];
            float b = tbase[idx];
            pv[j] = in ? a : 0.0f;
            tv[j] = in ? b : 0.0f;
        }
    }
}

__device__ __forceinline__ void pass_v_body(
    const float (&pv)[8], const float (&tv)[8], bf16x8 wfrag,
    unsigned short (*vb)[16][VBS], int n16, int vcol) {
    const f32x4 z = {0.0f, 0.0f, 0.0f, 0.0f};
    const f32x2 halfv = {0.5f, 0.5f};
    f32x2 p2[4], t2[4];
    #pragma unroll
    for (int h = 0; h < 4; ++h) {
        f32x2 pr = {pv[2*h], pv[2*h+1]};
        f32x2 tr = {tv[2*h], tv[2*h+1]};
        p2[h] = pr * halfv + halfv;     // v_pk_fma_f32
        t2[h] = tr * halfv + halfv;
    }
    #pragma unroll
    for (int ch = 0; ch < 5; ++ch) {
        union { bf16x8 v; unsigned int u[4]; } f;
        #pragma unroll
        for (int h = 0; h < 4; ++h) {
            f32x2 q;
            if      (ch == 0) q = p2[h];
            else if (ch == 1) q = t2[h];
            else if (ch == 2) q = p2[h] * p2[h];   // v_pk_mul_f32
            else if (ch == 3) q = t2[h] * t2[h];
            else              q = p2[h] * t2[h];
            f.u[h] = pkbf(q.x, q.y);
        }
        f32x4 d = __builtin_amdgcn_mfma_f32_16x16x32_bf16(f.v, wfrag, z, 0, 0, 0);
        union { ushort4 s; unsigned int u[2]; } pk;
        pk.u[0] = pkbf(d[0], d[1]);
        pk.u[1] = pkbf(d[2], d[3]);
        *(ushort4*)&vb[ch][n16][vcol] = pk.s;
    }
}

__device__ __forceinline__ float pass_h_body(
    unsigned short (*vb)[16][VBS], bf16x8 wfrag, int n16, int quad, int h) {
    const f32x4 z = {0.0f, 0.0f, 0.0f, 0.0f};
    float lsum = 0.0f;
    f32x4 r[5];
    #pragma unroll
    for (int ch = 0; ch < 5; ++ch) {
        bf16x8 a = *(const bf16x8*)&vb[ch][n16][16 * h + 8 * quad];
        r[ch] = __builtin_amdgcn_mfma_f32_16x16x32_bf16(a, wfrag, z, 0, 0, 0);
    }
    const f32x2 twov = {2.0f, 2.0f};
    const f32x2 c1v  = {C1c, C1c};
    const f32x2 c2v  = {C2c, C2c};
    #pragma unroll
    for (int jj = 0; jj < 2; ++jj) {
        f32x2 mp  = {r[0][2*jj], r[0][2*jj+1]};
        f32x2 mt  = {r[1][2*jj], r[1][2*jj+1]};
        f32x2 epp = {r[2][2*jj], r[2][2*jj+1]};
        f32x2 ett = {r[3][2*jj], r[3][2*jj+1]};
        f32x2 ept = {r[4][2*jj], r[4][2*jj+1]};
        f32x2 mp2 = mp * mp;
        f32x2 mt2 = mt * mt;
        f32x2 mpt = mp * mt;
        f32x2 sp_ = epp - mp2;
        f32x2 st_ = ett - mt2;
        f32x2 spt = ept - mpt;
        f32x2 num = (mpt * twov + c1v) * (spt * twov + c2v);
        f32x2 den = (mp2 + mt2 + c1v) * (sp_ + st_ + c2v);
        lsum = fmaf(num.x, __builtin_amdgcn_rcpf(den.x), lsum);
        lsum = fmaf(num.y, __builtin_amdgcn_rcpf(den.y), lsum);
    }
    return lsum;
}

// per-wave tile body: 5 pipelined V-chunks + 4 H-chunks, no barriers
__device__ __forceinline__ float wave_tile(
    const float* __restrict__ pbase, const float* __restrict__ tbase,
    int tx0, int ty0, bf16x8 wfrag,
    unsigned short (*vbw)[16][VBS], int n16, int quad) {

    const int gy0 = ty0 - 5 + quad * 8;
    const int gxb = tx0 - 5 + n16;          // chunk c column: gxb + 16c

    float pva[8], tva[8], pvb[8], tvb[8];
    load_px(pbase, tbase, gxb,      gy0, pva, tva);   // chunk 0
    load_px(pbase, tbase, gxb + 16, gy0, pvb, tvb);   // chunk 1 (in flight)
    pass_v_body(pva, tva, wfrag, vbw, n16,  0 + 4 * quad);
    load_px(pbase, tbase, gxb + 32, gy0, pva, tva);   // chunk 2
    pass_v_body(pvb, tvb, wfrag, vbw, n16, 16 + 4 * quad);
    load_px(pbase, tbase, gxb + 48, gy0, pvb, tvb);   // chunk 3
    pass_v_body(pva, tva, wfrag, vbw, n16, 32 + 4 * quad);
    load_px(pbase, tbase, gxb + 64, gy0, pva, tva);   // chunk 4
    pass_v_body(pvb, tvb, wfrag, vbw, n16, 48 + 4 * quad);
    pass_v_body(pva, tva, wfrag, vbw, n16, 64 + 4 * quad);
    // same-wave ds_write -> ds_read: compiler inserts counted lgkmcnt

    float lsum = 0.0f;
    #pragma unroll
    for (int h = 0; h < 4; ++h)
        lsum += pass_h_body(vbw, wfrag, n16, quad, h);
    return lsum;
}

// ---------------- main kernel, workspace path (R14) -----------------------

__global__ __launch_bounds__(128, 3) void ssim_main_ws(
    const float* __restrict__ pred,
    const float* __restrict__ target,
    const unsigned short* __restrict__ wtab,   // 16x32 bf16 W matrix in ws
    float* __restrict__ partials)              // NPART per-wave partials
{
    __shared__ unsigned short vb[2][5][16][VBS];  // 23040 B, disjoint halves

    const int tid  = threadIdx.x;
    const int w    = tid >> 6;
    const int lane = tid & 63;
    const int quad = lane >> 4;
    const int n16  = lane & 15;
    const int tx0  = blockIdx.x * 64;
    const int ty0  = (blockIdx.y * 2 + w) * 16;   // wave-private y tile
    const float* __restrict__ pbase = pred   + (size_t)blockIdx.z * (IMG * IMG);
    const float* __restrict__ tbase = target + (size_t)blockIdx.z * (IMG * IMG);

    const bf16x8 wfrag = *(const bf16x8*)(wtab + n16 * 32 + quad * 8);

    float lsum = wave_tile(pbase, tbase, tx0, ty0, wfrag, vb[w], n16, quad);

    #pragma unroll
    for (int off = 32; off > 0; off >>= 1)
        lsum += __shfl_down(lsum, off, 64);
    if (lane == 0) {
        int bid = blockIdx.x + GXD * (blockIdx.y + GYD * blockIdx.z);
        partials[bid * 2 + w] = lsum;
    }
}

// W-table init on device
__global__ void ssim_winit(unsigned short* __restrict__ wtab, GaussB gwb) {
    int idx = threadIdx.x;            // 512 threads
    int i = idx >> 5, k = idx & 31, d = k - i;
    wtab[idx] = (d >= 0 && d <= 10) ? gwb.gb[d] : 0;
}

// ---------------- atomic fallback (ws too small) --------------------------

__global__ __launch_bounds__(128, 3) void ssim_main_atomic(
    const float* __restrict__ pred,
    const float* __restrict__ target,
    float* __restrict__ sink,
    GaussB gwb)
{
    __shared__ unsigned short Wmat[16][32];
    __shared__ unsigned short vb[2][5][16][VBS];

    const int tid  = threadIdx.x;
    const int w    = tid >> 6;
    const int lane = tid & 63;
    const int quad = lane >> 4;
    const int n16  = lane & 15;
    const int tx0  = blockIdx.x * 64;
    const int ty0  = (blockIdx.y * 2 + w) * 16;
    const float* __restrict__ pbase = pred   + (size_t)blockIdx.z * (IMG * IMG);
    const float* __restrict__ tbase = target + (size_t)blockIdx.z * (IMG * IMG);

    #pragma unroll
    for (int r = 0; r < 4; ++r) {
        int idx = tid + 128 * r;
        int i = idx >> 5, k = idx & 31, d = k - i;
        Wmat[i][k] = (d >= 0 && d <= 10) ? gwb.gb[d] : 0;
    }
    __syncthreads();
    const bf16x8 wfrag = *(const bf16x8*)&Wmat[n16][quad * 8];

    float lsum = wave_tile(pbase, tbase, tx0, ty0, wfrag, vb[w], n16, quad);

    #pragma unroll
    for (int off = 32; off > 0; off >>= 1)
        lsum += __shfl_down(lsum, off, 64);
    if (lane == 0)
        atomicAdd(sink, lsum);
}

// ---------------- reductions ----------------------------------------------

__global__ __launch_bounds__(1024) void ssim_reduce(const float* __restrict__ partials,
                                                    float* __restrict__ out)
{
    __shared__ float red[16];
    const int tid = threadIdx.x;
    float s = 0.0f;
    const float4* p4 = (const float4*)partials;
    #pragma unroll
    for (int j = 0; j < NPART / 4096; ++j) {   // 12288/4 = 3072 f4 / 1024
        float4 v = p4[tid + 1024 * j];
        s += v.x + v.y + v.z + v.w;
    }
    #pragma unroll
    for (int off = 32; off > 0; off >>= 1)
        s += __shfl_down(s, off, 64);
    if ((tid & 63) == 0) red[tid >> 6] = s;
    __syncthreads();
    if (tid == 0) {
        float t = 0.0f;
        #pragma unroll
        for (int k = 0; k < 16; ++k) t += red[k];
        out[0] = 1.0f - t / NTOTAL;
    }
}

__global__ void ssim_zero(float* accum) { accum[0] = 0.0f; }
__global__ void ssim_final(const float* accum, float* out) {
    out[0] = 1.0f - accum[0] / NTOTAL;
}

// ---------------- host ----------------------------------------------------

extern "C" void kernel_launch(void* const* d_in, const int* in_sizes, int n_in,
                              void* d_out, int out_size, void* d_ws, size_t ws_size,
                              hipStream_t stream) {
    const float* pred   = (const float*)d_in[0];
    const float* target = (const float*)d_in[1];
    float* out = (float*)d_out;

    // Gaussian weights in double, RNE-rounded to bf16 on host
    GaussB gwb;
    double vals[11], s = 0.0;
    for (int i = 0; i < 11; ++i) {
        double d = (double)i - 5.0;
        vals[i] = exp(-(d * d) / (2.0 * 1.5 * 1.5));
        s += vals[i];
    }
    for (int i = 0; i < 11; ++i) {
        float f = (float)(vals[i] / s);
        unsigned int u;
        __builtin_memcpy(&u, &f, 4);
        unsigned int rounded = (u + 0x7FFFu + ((u >> 16) & 1u)) >> 16;  // RNE
        gwb.gb[i] = (unsigned short)rounded;
    }

    dim3 grid(GXD, GYD, GZD);   // 8 x 16 x 48 = 6144 blocks, 2 waves each
    if (ws_size >= WS_NEED) {
        unsigned short* wtab = (unsigned short*)d_ws;            // 1 KB
        float* partials = (float*)((char*)d_ws + 1024);          // NPART floats
        ssim_winit<<<1, 512, 0, stream>>>(wtab, gwb);
        ssim_main_ws<<<grid, 128, 0, stream>>>(pred, target, wtab, partials);
        ssim_reduce<<<1, 1024, 0, stream>>>(partials, out);
    } else {
        float* accum = (float*)d_ws;
        ssim_zero<<<1, 1, 0, stream>>>(accum);
        ssim_main_atomic<<<grid, 128, 0, stream>>>(pred, target, accum, gwb);
        ssim_final<<<1, 1, 0, stream>>>(accum, out);
    }
}